// Round 10
// baseline (238.064 us; speedup 1.0000x reference)
//
#include <hip/hip_runtime.h>
#include <math.h>

// Problem constants (match the jax reference)
constexpr int B_  = 2;
constexpr int C_  = 64;
constexpr int HW_ = 64 * 128;      // 8192
constexpr int N_  = HW_;           // points per image (near == far == 8192)
constexpr int NX_ = 512;
constexpr int NY_ = 512;
constexpr int NYNX_ = NX_ * NY_;   // 262144
constexpr int SEG_  = 64;          // near-dim segments (partial top-3 per seg)
constexpr int SEGN_ = N_ / SEG_;   // 128 near candidates per segment
constexpr int FPT_  = 2;           // far points per thread in nn_part
                                   // (R8: FPT=4 @4 blocks/CU regressed; 8 blocks/CU wins)
constexpr int BN_   = B_ * N_;     // 16384

// ---------------------------------------------------------------------------
// Shared voxel binning (numpy f32 bitwise). -1 = contributes nothing.
// ---------------------------------------------------------------------------
__device__ __forceinline__ int voxel_of(float x, float y, float w) {
#pragma clang fp contract(off)
  if (w == 0.0f) return -1;
  float qx = (x - 0.0f) / 0.1f;
  float qy = (y - (-25.6f)) / 0.1f;
  int ix = (int)floorf(qx);
  int iy = (int)floorf(qy);
  if (ix < 0 || ix >= NX_ || iy < 0 || iy >= NY_) return -1;
  return iy * NX_ + ix;
}

// ---------------------------------------------------------------------------
// Fused prep: blocks [0,64) pack+count points; blocks [64,320) transpose
// fv (B,C,HW) -> fvT (B,HW,C). The two halves are independent.
// ---------------------------------------------------------------------------
__global__ __launch_bounds__(256) void prep_kernel(
    const float* __restrict__ fv,
    const float* __restrict__ pi, const int* __restrict__ pm,
    const float* __restrict__ pif, const int* __restrict__ pmf,
    float4* __restrict__ near4, float4* __restrict__ far4,
    float4* __restrict__ nearnn, float* __restrict__ cnt,
    float* __restrict__ fvT) {
#pragma clang fp contract(off)
  __shared__ float tile[64][65];
  if (blockIdx.x < 64) {
    // ---- pack + count ----
    int t = blockIdx.x * 256 + threadIdx.x;        // over B_*N_
    int k = t / N_, n = t % N_;
    const float* base  = pi  + (size_t)k * 4 * HW_;
    const float* basef = pif + (size_t)k * 4 * HW_;
    float x = base[n], y = base[HW_ + n], z = base[2 * HW_ + n];
    bool v = pm[k * HW_ + n] > 0;
    near4[t] = make_float4(x, y, z, v ? 1.0f : 0.0f);
    float sq = (x * x + y * y) + z * z;   // numpy 3-elem sum order
    nearnn[t] = v ? make_float4(x, y, z, sq)
                 : make_float4(0.0f, 0.0f, 0.0f, 1e10f);
    float fx = basef[n], fy = basef[HW_ + n], fz = basef[2 * HW_ + n];
    bool vf = pmf[k * HW_ + n] > 0;
    far4[t] = make_float4(fx, fy, fz, vf ? 1.0f : 0.0f);

    int vn = voxel_of(x, y, v ? 1.0f : 0.0f);
    if (vn >= 0) atomicAdd(&cnt[(size_t)k * NYNX_ + vn], 1.0f);
    int vfv = voxel_of(fx, fy, vf ? 1.0f : 0.0f);
    if (vfv >= 0) atomicAdd(&cnt[(size_t)k * NYNX_ + vfv], 1.0f);
  } else {
    // ---- transpose ----
    int bid = blockIdx.x - 64;          // 0..255
    int k = bid >> 7;                   // /128
    int n0 = (bid & 127) * 64;
    int tx = threadIdx.x & 63, ty = threadIdx.x >> 6;
    for (int c = ty; c < C_; c += 4)
      tile[c][tx] = fv[((size_t)(k * C_ + c)) * HW_ + n0 + tx];
    __syncthreads();
    for (int nn = ty; nn < 64; nn += 4)
      fvT[((size_t)(k * HW_ + n0 + nn)) * C_ + tx] = tile[tx][nn];
  }
}

// ---------------------------------------------------------------------------
// Stable top-3 insert, value path (min + 2x med3) + index path (3 cmp +
// 5 cndmask). Case-exhaustively identical to the verified merge3: candidate
// loses ties; displaced incumbents shift down with their indices.
// ---------------------------------------------------------------------------
__device__ __forceinline__ void merge3_fast(float tv, int idx,
                                            float& b0, float& b1, float& b2,
                                            int& i0, int& i1, int& i2) {
  bool c0 = tv < b0;
  bool c1 = tv < b1;
  bool c2 = tv < b2;
  float nb0 = fminf(b0, tv);
  float nb1 = __builtin_amdgcn_fmed3f(b0, b1, tv);
  float nb2 = __builtin_amdgcn_fmed3f(b1, b2, tv);
  int oi0 = i0, oi1 = i1;
  i0 = c0 ? idx : i0;
  i1 = c0 ? oi0 : (c1 ? idx : i1);
  i2 = c1 ? oi1 : (c2 ? idx : i2);
  b0 = nb0; b1 = nb1; b2 = nb2;
}

// Full cndmask variant (merge paths where op count doesn't matter).
__device__ __forceinline__ void merge3(float tv, int idx,
                                       float& b0, float& b1, float& b2,
                                       int& i0, int& i1, int& i2) {
  bool c0 = tv < b0;
  bool c1 = tv < b1;
  bool c2 = tv < b2;
  float ob0 = b0, ob1 = b1;
  int   oi0 = i0, oi1 = i1;
  b0 = c0 ? tv : b0;                    i0 = c0 ? idx : i0;
  b1 = c0 ? ob0 : (c1 ? tv : b1);       i1 = c0 ? oi0 : (c1 ? idx : i1);
  b2 = c1 ? ob1 : (c2 ? tv : b2);       i2 = c1 ? oi1 : (c2 ? idx : i2);
}

// ---------------------------------------------------------------------------
// Partial 3-NN: 2 far points per thread. The candidate segment is read with
// a WAVE-UNIFORM index directly from global memory -> compiler emits scalar
// s_load (SMEM pipe), removing the LDS tile, its ds_read issue slots, and
// the staging barrier entirely. d2 replicates the reference f32 bitwise:
// (sf + sq_near) - fma(az,qz, fma(ay,qy, ax*qx)).
// Partials stored SEGMENT-MAJOR: pd[(s*3+slot)*BN + g] for coalesced merge.
// Grid (16,64,2) = 2048 blocks = 8 blocks/CU = 32 waves/CU.
// ---------------------------------------------------------------------------
__global__ __launch_bounds__(256, 8) void nn_part_kernel(
    const float4* __restrict__ nearnn, const float4* __restrict__ far4,
    float* __restrict__ pd, int* __restrict__ pidx) {
#pragma clang fp contract(off)
  int t = threadIdx.x;
  int fb = blockIdx.x;           // 0..15  far block (512 far points each)
  int s  = blockIdx.y;           // 0..SEG_-1
  int k  = blockIdx.z;           // batch

  const float4* seg = nearnn + k * N_ + s * SEGN_;   // wave-uniform base

  int m0 = fb * (256 * FPT_) + t;
  int m1 = m0 + 256;
  float4 f0 = far4[k * N_ + m0];
  float4 f1 = far4[k * N_ + m1];
  float sf0 = (f0.x * f0.x + f0.y * f0.y) + f0.z * f0.z;  // numpy 3-elem order
  float sf1 = (f1.x * f1.x + f1.y * f1.y) + f1.z * f1.z;
  float ax0 = 2.0f * f0.x, ay0 = 2.0f * f0.y, az0 = 2.0f * f0.z;
  float ax1 = 2.0f * f1.x, ay1 = 2.0f * f1.y, az1 = 2.0f * f1.z;

  float a0 = 1e30f, a1 = 1e30f, a2 = 1e30f;
  float b0 = 1e30f, b1 = 1e30f, b2 = 1e30f;
  int ia0 = 0, ia1 = 0, ia2 = 0;
  int ib0 = 0, ib1 = 0, ib2 = 0;
  int base_idx = s * SEGN_;
#pragma unroll 4
  for (int i = 0; i < SEGN_; ++i) {
    float4 q = seg[i];                                   // uniform -> s_load
    int idx = base_idx + i;
    float p0 = ax0 * q.x;                                  // round(ax*qx)
    float mm0 = __builtin_fmaf(az0, q.z, __builtin_fmaf(ay0, q.y, p0));
    float tv0 = (sf0 + q.w) - mm0;                         // masked -> ~1e10
    merge3_fast(tv0, idx, a0, a1, a2, ia0, ia1, ia2);
    float p1 = ax1 * q.x;
    float mm1 = __builtin_fmaf(az1, q.z, __builtin_fmaf(ay1, q.y, p1));
    float tv1 = (sf1 + q.w) - mm1;
    merge3_fast(tv1, idx, b0, b1, b2, ib0, ib1, ib2);
  }

  int g0 = k * N_ + m0, g1 = k * N_ + m1;
  int jb = s * 3;
  pd[(size_t)(jb + 0) * BN_ + g0] = a0;
  pd[(size_t)(jb + 1) * BN_ + g0] = a1;
  pd[(size_t)(jb + 2) * BN_ + g0] = a2;
  pidx[(size_t)(jb + 0) * BN_ + g0] = ia0;
  pidx[(size_t)(jb + 1) * BN_ + g0] = ia1;
  pidx[(size_t)(jb + 2) * BN_ + g0] = ia2;
  pd[(size_t)(jb + 0) * BN_ + g1] = b0;
  pd[(size_t)(jb + 1) * BN_ + g1] = b1;
  pd[(size_t)(jb + 2) * BN_ + g1] = b2;
  pidx[(size_t)(jb + 0) * BN_ + g1] = ib0;
  pidx[(size_t)(jb + 1) * BN_ + g1] = ib1;
  pidx[(size_t)(jb + 2) * BN_ + g1] = ib2;
}

// ---------------------------------------------------------------------------
// Fused mid: blocks [0,256) merge the SEG_*3 partials per far point (4
// threads/far, contiguous ascending j-ranges preserve the lowest-index tie
// rule); blocks [256,2304) zero acc rows where cnt>=2. Independent halves.
// ---------------------------------------------------------------------------
__global__ __launch_bounds__(256) void mid_kernel(
    const float* __restrict__ pd, const int* __restrict__ pidx,
    int* __restrict__ nn_idx, float* __restrict__ nn_w,
    const float* __restrict__ cnt, float* __restrict__ acc) {
#pragma clang fp contract(off)
  constexpr int Q = 4;                   // threads per far point
  constexpr int J = SEG_ * 3 / Q;        // 48 candidates per thread
  __shared__ float md[Q][64][3];
  __shared__ int   mi[Q][64][3];
  if (blockIdx.x < 256) {
    int t = threadIdx.x;
    int q  = t >> 6;                       // 0..3
    int gl = t & 63;
    int g = blockIdx.x * 64 + gl;          // far point id (over BN_)

    float b0 = 1e30f, b1 = 1e30f, b2 = 1e30f;
    int i0 = 0, i1 = 0, i2 = 0;
    int j0 = q * J;
    for (int j = 0; j < J; ++j) {
      float d = pd[(size_t)(j0 + j) * BN_ + g];
      int   ix = pidx[(size_t)(j0 + j) * BN_ + g];
      merge3(d, ix, b0, b1, b2, i0, i1, i2);
    }
    md[q][gl][0] = b0; md[q][gl][1] = b1; md[q][gl][2] = b2;
    mi[q][gl][0] = i0; mi[q][gl][1] = i1; mi[q][gl][2] = i2;
    __syncthreads();

    if (q == 0) {
      float c0 = 1e30f, c1 = 1e30f, c2 = 1e30f;
      int k0 = 0, k1 = 0, k2 = 0;
      for (int qq = 0; qq < Q; ++qq)
        for (int j = 0; j < 3; ++j)
          merge3(md[qq][gl][j], mi[qq][gl][j], c0, c1, c2, k0, k1, k2);
      float r0 = 1.0f / (c0 + 1e-8f);
      float r1 = 1.0f / (c1 + 1e-8f);
      float r2 = 1.0f / (c2 + 1e-8f);
      float rs = (r0 + r1) + r2;
      int o = g * 3;
      nn_idx[o] = k0; nn_idx[o + 1] = k1; nn_idx[o + 2] = k2;
      nn_w[o] = r0 / rs; nn_w[o + 1] = r1 / rs; nn_w[o + 2] = r2 / rs;
    }
  } else {
    // ---- zero collision rows (~130/batch) ----
    int t = (blockIdx.x - 256) * 256 + threadIdx.x;  // over B_*NYNX_
    if (cnt[t] >= 2.0f) {
      float4* row = (float4*)(acc + (size_t)t * C_);
      float4 z = make_float4(0.0f, 0.0f, 0.0f, 0.0f);
      for (int i = 0; i < C_ / 4; ++i) row[i] = z;
    }
  }
}

// ---------------------------------------------------------------------------
// Scatter features into voxel-major acc (k,v,C). Wave per point, lane =
// channel. cnt==1 (98%): plain coalesced store. cnt>=2: row atomics.
// ---------------------------------------------------------------------------
__global__ __launch_bounds__(256) void scatter_feat_kernel(
    const float4* __restrict__ near4, const float4* __restrict__ far4,
    const float* __restrict__ fvT,
    const int* __restrict__ nn_idx, const float* __restrict__ nn_w,
    const float* __restrict__ cnt, float* __restrict__ acc) {
#pragma clang fp contract(off)
  int lane = threadIdx.x & 63;
  int wv = blockIdx.x * 4 + (threadIdx.x >> 6);  // global wave id = point slot
  int k = wv / (2 * N_);
  int p = wv % (2 * N_);
  bool is_far = p >= N_;
  int n = is_far ? p - N_ : p;

  float4 pt = is_far ? far4[k * N_ + n] : near4[k * N_ + n];
  int v = voxel_of(pt.x, pt.y, pt.w);
  if (v < 0) return;

  float val;
  if (!is_far) {
    val = fvT[((size_t)(k * N_ + n)) * C_ + lane];
  } else {
    int o = (k * N_ + n) * 3;
    int i0 = nn_idx[o], i1 = nn_idx[o + 1], i2 = nn_idx[o + 2];
    float w0 = nn_w[o], w1 = nn_w[o + 1], w2 = nn_w[o + 2];
    val = w0 * fvT[((size_t)(k * N_ + i0)) * C_ + lane]
        + w1 * fvT[((size_t)(k * N_ + i1)) * C_ + lane]
        + w2 * fvT[((size_t)(k * N_ + i2)) * C_ + lane];
  }
  size_t rowoff = ((size_t)k * NYNX_ + v) * C_;
  float cn = cnt[(size_t)k * NYNX_ + v];   // wave-uniform
  if (cn == 1.0f) acc[rowoff + lane] = val;
  else            atomicAdd(&acc[rowoff + lane], val);
}

// ---------------------------------------------------------------------------
// Emit out (B,C,NY,NX) from acc/cnt via LDS transpose. Per block: 64 voxels.
// Phase 1: coalesced float4 row-gathers of occupied rows (divide fused),
// zeros otherwise. Phase 2: coalesced float4 out stores. Covers every out
// element exactly once (fuses the zero-fill).
// ---------------------------------------------------------------------------
__global__ __launch_bounds__(256) void emit_kernel(
    const float* __restrict__ acc, const float* __restrict__ cnt,
    float* __restrict__ out) {
#pragma clang fp contract(off)
  __shared__ float tile[64][65];
  __shared__ float cs[64];
  int t = threadIdx.x;
  int k = blockIdx.y;
  int v0 = blockIdx.x * 64;

  if (t < 64) cs[t] = cnt[(size_t)k * NYNX_ + v0 + t];
  __syncthreads();

  const float4* acc4 = (const float4*)acc;
#pragma unroll
  for (int p = 0; p < 4; ++p) {
    int row = p * 16 + (t >> 4);     // voxel within block
    int f4  = t & 15;                // float4 within the 64-channel row
    float c = cs[row];
    float4 a = make_float4(0.0f, 0.0f, 0.0f, 0.0f);
    if (c > 0.0f) {
      a = acc4[((size_t)k * NYNX_ + v0 + row) * (C_ / 4) + f4];
      a.x /= c; a.y /= c; a.z /= c; a.w /= c;
    }
    tile[f4 * 4 + 0][row] = a.x;
    tile[f4 * 4 + 1][row] = a.y;
    tile[f4 * 4 + 2][row] = a.z;
    tile[f4 * 4 + 3][row] = a.w;
  }
  __syncthreads();

#pragma unroll
  for (int p = 0; p < 4; ++p) {
    int c  = p * 16 + (t >> 4);      // channel
    int xq = t & 15;                 // float4 of voxels
    float4 o = make_float4(tile[c][xq * 4 + 0], tile[c][xq * 4 + 1],
                           tile[c][xq * 4 + 2], tile[c][xq * 4 + 3]);
    ((float4*)out)[(((size_t)k * C_ + c) * NYNX_ + v0) / 4 + xq] = o;
  }
}

extern "C" void kernel_launch(void* const* d_in, const int* in_sizes, int n_in,
                              void* d_out, int out_size, void* d_ws, size_t ws_size,
                              hipStream_t stream) {
  const float* fv  = (const float*)d_in[0];  // (B,C,H,W)
  const float* pi  = (const float*)d_in[1];  // (B,4,H,W)
  const int*   pm  = (const int*)d_in[2];    // (B,H,W)
  const float* pif = (const float*)d_in[3];  // (B,4,H,W)
  const int*   pmf = (const int*)d_in[4];    // (B,H,W)
  float* out = (float*)d_out;                // (B,C,NY,NX) f32

  // workspace layout (16B aligned): small buffers ~7.5 MB, acc 134 MB at +8MB.
  char* wsb = (char*)d_ws;
  float*  fvT    = (float*)(wsb);                 // B*HW*C*4      = 4,194,304
  float*  cnt    = (float*)(wsb + 4194304);       // B*NYNX*4      = 2,097,152
  float4* near4  = (float4*)(wsb + 6291456);      // B*N*16        =   262,144
  float4* far4   = (float4*)(wsb + 6553600);      // B*N*16        =   262,144
  float4* nearnn = (float4*)(wsb + 6815744);      // B*N*16        =   262,144
  int*    nnidx  = (int*)(wsb + 7077888);         // B*N*3*4       =   196,608
  float*  nnw    = (float*)(wsb + 7274496);       // B*N*3*4       =   196,608
  float*  acc    = (float*)(wsb + 8388608);       // B*NYNX*C*4    = 134,217,728

  // Partial top-3 buffers live in d_out's head (consumed by mid_kernel before
  // emit overwrites out): pd 12.6 MB + pidx 12.6 MB (segment-major).
  float* pd   = out;
  int*   pidx = (int*)(out + (size_t)SEG_ * 3 * BN_);

  hipMemsetAsync(cnt, 0, (size_t)B_ * NYNX_ * sizeof(float), stream);

  prep_kernel<<<320, 256, 0, stream>>>(
      fv, pi, pm, pif, pmf, near4, far4, nearnn, cnt, fvT);
  nn_part_kernel<<<dim3(N_ / (256 * FPT_), SEG_, B_), 256, 0, stream>>>(
      nearnn, far4, pd, pidx);
  mid_kernel<<<256 + B_ * NYNX_ / 256, 256, 0, stream>>>(
      pd, pidx, nnidx, nnw, cnt, acc);
  scatter_feat_kernel<<<B_ * 2 * N_ / 4, 256, 0, stream>>>(
      near4, far4, fvT, nnidx, nnw, cnt, acc);
  emit_kernel<<<dim3(NYNX_ / 64, B_), 256, 0, stream>>>(acc, cnt, out);
}

// Round 11
// 215.206 us; speedup vs baseline: 1.1062x; 1.1062x over previous
//
#include <hip/hip_runtime.h>
#include <math.h>

// Problem constants (match the jax reference)
constexpr int B_  = 2;
constexpr int C_  = 64;
constexpr int HW_ = 64 * 128;      // 8192
constexpr int N_  = HW_;           // points per image (near == far == 8192)
constexpr int NX_ = 512;
constexpr int NY_ = 512;
constexpr int NYNX_ = NX_ * NY_;   // 262144
constexpr int GC_  = 32;           // NN search grid is GC x GC cells of 1.6 m
constexpr int GCC_ = GC_ * GC_;    // 1024 cells

// ---------------------------------------------------------------------------
// Shared voxel binning (numpy f32 bitwise). -1 = contributes nothing.
// ---------------------------------------------------------------------------
__device__ __forceinline__ int voxel_of(float x, float y, float w) {
#pragma clang fp contract(off)
  if (w == 0.0f) return -1;
  float qx = (x - 0.0f) / 0.1f;
  float qy = (y - (-25.6f)) / 0.1f;
  int ix = (int)floorf(qx);
  int iy = (int)floorf(qy);
  if (ix < 0 || ix >= NX_ || iy < 0 || iy >= NY_) return -1;
  return iy * NX_ + ix;
}

// NN-grid cell coords (internal only — must be identical in build & search).
__device__ __forceinline__ int gcell_x(float x) {
  int c = (int)floorf(x * 0.625f);          // /1.6
  return min(GC_ - 1, max(0, c));
}
__device__ __forceinline__ int gcell_y(float y) {
  int c = (int)floorf((y + 25.6f) * 0.625f);
  return min(GC_ - 1, max(0, c));
}

// ---------------------------------------------------------------------------
// Fused prep: blocks [0,64) pack+count points; blocks [64,320) transpose
// fv (B,C,HW) -> fvT (B,HW,C). The two halves are independent.
// ---------------------------------------------------------------------------
__global__ __launch_bounds__(256) void prep_kernel(
    const float* __restrict__ fv,
    const float* __restrict__ pi, const int* __restrict__ pm,
    const float* __restrict__ pif, const int* __restrict__ pmf,
    float4* __restrict__ near4, float4* __restrict__ far4,
    float4* __restrict__ nearnn, float* __restrict__ cnt,
    float* __restrict__ fvT) {
#pragma clang fp contract(off)
  __shared__ float tile[64][65];
  if (blockIdx.x < 64) {
    // ---- pack + count ----
    int t = blockIdx.x * 256 + threadIdx.x;        // over B_*N_
    int k = t / N_, n = t % N_;
    const float* base  = pi  + (size_t)k * 4 * HW_;
    const float* basef = pif + (size_t)k * 4 * HW_;
    float x = base[n], y = base[HW_ + n], z = base[2 * HW_ + n];
    bool v = pm[k * HW_ + n] > 0;
    near4[t] = make_float4(x, y, z, v ? 1.0f : 0.0f);
    float sq = (x * x + y * y) + z * z;   // numpy 3-elem sum order
    nearnn[t] = v ? make_float4(x, y, z, sq)
                 : make_float4(0.0f, 0.0f, 0.0f, 1e10f);
    float fx = basef[n], fy = basef[HW_ + n], fz = basef[2 * HW_ + n];
    bool vf = pmf[k * HW_ + n] > 0;
    far4[t] = make_float4(fx, fy, fz, vf ? 1.0f : 0.0f);

    int vn = voxel_of(x, y, v ? 1.0f : 0.0f);
    if (vn >= 0) atomicAdd(&cnt[(size_t)k * NYNX_ + vn], 1.0f);
    int vfv = voxel_of(fx, fy, vf ? 1.0f : 0.0f);
    if (vfv >= 0) atomicAdd(&cnt[(size_t)k * NYNX_ + vfv], 1.0f);
  } else {
    // ---- transpose ----
    int bid = blockIdx.x - 64;          // 0..255
    int k = bid >> 7;                   // /128
    int n0 = (bid & 127) * 64;
    int tx = threadIdx.x & 63, ty = threadIdx.x >> 6;
    for (int c = ty; c < C_; c += 4)
      tile[c][tx] = fv[((size_t)(k * C_ + c)) * HW_ + n0 + tx];
    __syncthreads();
    for (int nn = ty; nn < 64; nn += 4)
      fvT[((size_t)(k * HW_ + n0 + nn)) * C_ + tx] = tile[tx][nn];
  }
}

// ---------------------------------------------------------------------------
// Lexicographic stable top-3 insert on (value, index): lower value wins,
// ties broken by lower index. Order-INDEPENDENT (safe for arbitrary candidate
// order) and equal to jax stable top-k. Invariant: slots lex-sorted.
// ---------------------------------------------------------------------------
__device__ __forceinline__ void merge3L(float tv, int idx,
                                        float& b0, float& b1, float& b2,
                                        int& i0, int& i1, int& i2) {
  bool w0 = (tv < b0) || (tv == b0 && idx < i0);
  bool w1 = (tv < b1) || (tv == b1 && idx < i1);
  bool w2 = (tv < b2) || (tv == b2 && idx < i2);
  float ob0 = b0, ob1 = b1;
  int   oi0 = i0, oi1 = i1;
  b0 = w0 ? tv : b0;                    i0 = w0 ? idx : i0;
  b1 = w0 ? ob0 : (w1 ? tv : b1);       i1 = w0 ? oi0 : (w1 ? idx : i1);
  b2 = w1 ? ob1 : (w2 ? tv : b2);       i2 = w1 ? oi1 : (w2 ? idx : i2);
}

// ---------------------------------------------------------------------------
// build_grid: blocks [0,B_) bin VALID near points into the 32x32 cell grid
// (LDS count -> LDS scan -> global CSR + LDS-cursor fill). Within-cell order
// is arbitrary (atomic) — harmless, selection is lexicographic.
// Blocks [B_, B_+2048): zero acc rows where cnt>=2 (~130 voxels/batch).
// ---------------------------------------------------------------------------
__global__ __launch_bounds__(256) void build_grid_kernel(
    const float4* __restrict__ nearnn, const float* __restrict__ cnt,
    int* __restrict__ cell_start, float4* __restrict__ gpts,
    int* __restrict__ gidx, float* __restrict__ acc) {
  __shared__ int lcnt[GCC_];
  __shared__ int lsum[256];
  __shared__ int lcur[GCC_];
  int t = threadIdx.x;
  if (blockIdx.x < (unsigned)B_) {
    int k = blockIdx.x;
    for (int i = t; i < GCC_; i += 256) lcnt[i] = 0;
    __syncthreads();
    for (int n = t; n < N_; n += 256) {
      float4 q = nearnn[k * N_ + n];
      if (q.w < 1e9f)
        atomicAdd(&lcnt[gcell_y(q.y) * GC_ + gcell_x(q.x)], 1);
    }
    __syncthreads();
    // scan: per-thread 4-elem serial + Hillis-Steele over 256 partials
    int base = t * 4;
    int c0 = lcnt[base], c1 = lcnt[base + 1], c2 = lcnt[base + 2], c3 = lcnt[base + 3];
    int s = c0 + c1 + c2 + c3;
    lsum[t] = s;
    __syncthreads();
    for (int off = 1; off < 256; off <<= 1) {
      int v = (t >= off) ? lsum[t - off] : 0;
      __syncthreads();
      lsum[t] += v;
      __syncthreads();
    }
    int ex = lsum[t] - s;                 // exclusive prefix of this thread's 4
    lcnt[base] = ex;
    lcnt[base + 1] = ex + c0;
    lcnt[base + 2] = ex + c0 + c1;
    lcnt[base + 3] = ex + c0 + c1 + c2;
    __syncthreads();
    for (int i = t; i < GCC_; i += 256) {
      cell_start[k * (GCC_ + 1) + i] = lcnt[i];
      lcur[i] = lcnt[i];
    }
    if (t == 255) cell_start[k * (GCC_ + 1) + GCC_] = lsum[255];
    __syncthreads();
    // fill
    for (int n = t; n < N_; n += 256) {
      float4 q = nearnn[k * N_ + n];
      if (q.w < 1e9f) {
        int c = gcell_y(q.y) * GC_ + gcell_x(q.x);
        int p = atomicAdd(&lcur[c], 1);
        gpts[k * N_ + p] = q;
        gidx[k * N_ + p] = n;
      }
    }
  } else {
    int tt = (blockIdx.x - B_) * 256 + t;   // over B_*NYNX_
    if (cnt[tt] >= 2.0f) {
      float4* row = (float4*)(acc + (size_t)tt * C_);
      float4 z = make_float4(0.0f, 0.0f, 0.0f, 0.0f);
      for (int i = 0; i < C_ / 4; ++i) row[i] = z;
    }
  }
}

// ---------------------------------------------------------------------------
// nn_search: exact 3-NN via expanding Chebyshev rings over the cell grid.
// 4 lanes cooperate per far point (lane q takes ring-cells i%4==q).
// Every candidate is scored with the bitwise reference f32 formula; stable
// lexicographic top-3. Stop bound: after finishing ring r, any unvisited
// point has true-d2 >= (r*1.6)^2 and formula-d2 >= true-d2 - ~2e-3, so
// (r*1.6)^2 > quad_min(b2) + 0.01 guarantees no unvisited winner.
// ---------------------------------------------------------------------------
__global__ __launch_bounds__(256) void nn_search_kernel(
    const float4* __restrict__ far4, const int* __restrict__ cell_start,
    const float4* __restrict__ gpts, const int* __restrict__ gidx,
    int* __restrict__ nn_idx, float* __restrict__ nn_w) {
#pragma clang fp contract(off)
  int tid = threadIdx.x;
  int q = tid & 3;
  int g = blockIdx.x * 64 + (tid >> 2);   // far point id over BN
  int k = g >> 13;                        // /8192
  int m = g & (N_ - 1);

  float4 f = far4[k * N_ + m];
  float sf = (f.x * f.x + f.y * f.y) + f.z * f.z;   // numpy 3-elem order
  float ax = 2.0f * f.x, ay = 2.0f * f.y, az = 2.0f * f.z;
  int fcx = gcell_x(f.x), fcy = gcell_y(f.y);
  const int* cs_ = cell_start + k * (GCC_ + 1);

  float b0 = 1e30f, b1 = 1e30f, b2 = 1e30f;
  int i0 = 0, i1 = 0, i2 = 0;

  for (int r = 0; r < GC_; ++r) {
    int nc = (r == 0) ? 1 : 8 * r;
    for (int i = q; i < nc; i += 4) {
      int dx, dy;
      if (r == 0)            { dx = 0;             dy = 0; }
      else if (i < 2*r + 1)  { dx = i - r;         dy = -r; }
      else if (i < 4*r + 2)  { dx = i - (3*r + 1); dy = r; }
      else if (i < 6*r + 1)  { dx = -r;            dy = i - (5*r + 1); }
      else                   { dx = r;             dy = i - 7*r; }
      int cx = fcx + dx, cy = fcy + dy;
      if (cx < 0 || cx >= GC_ || cy < 0 || cy >= GC_) continue;
      int c = cy * GC_ + cx;
      int s = cs_[c], e = cs_[c + 1];
      for (int j = s; j < e; ++j) {
        float4 p = gpts[k * N_ + j];
        int idx = gidx[k * N_ + j];
        float p0 = ax * p.x;                                  // round(ax*px)
        float mm = __builtin_fmaf(az, p.z, __builtin_fmaf(ay, p.y, p0));
        float tv = (sf + p.w) - mm;
        merge3L(tv, idx, b0, b1, b2, i0, i1, i2);
      }
    }
    // quad-shared conservative bound (min of lanes' 3rd-best; 1e30 until
    // some lane holds 3 -> keep expanding, always safe)
    float s2 = b2;
    s2 = fminf(s2, __shfl_xor(s2, 1));
    s2 = fminf(s2, __shfl_xor(s2, 2));
    float rd = (float)r * 1.6f;
    if (rd * rd > s2 + 0.01f) break;
  }

  // quad merge: lane 0 folds lanes 1..3 (lexicographic, order-independent)
  int base = tid & ~3;
  for (int s = 1; s < 4; ++s) {
    float v0 = __shfl(b0, base + s), v1 = __shfl(b1, base + s), v2 = __shfl(b2, base + s);
    int   j0 = __shfl(i0, base + s), j1 = __shfl(i1, base + s), j2 = __shfl(i2, base + s);
    if (q == 0) {
      merge3L(v0, j0, b0, b1, b2, i0, i1, i2);
      merge3L(v1, j1, b0, b1, b2, i0, i1, i2);
      merge3L(v2, j2, b0, b1, b2, i0, i1, i2);
    }
  }
  if (q == 0) {
    float r0 = 1.0f / (b0 + 1e-8f);
    float r1 = 1.0f / (b1 + 1e-8f);
    float r2 = 1.0f / (b2 + 1e-8f);
    float rs = (r0 + r1) + r2;
    int o = g * 3;
    nn_idx[o] = i0; nn_idx[o + 1] = i1; nn_idx[o + 2] = i2;
    nn_w[o] = r0 / rs; nn_w[o + 1] = r1 / rs; nn_w[o + 2] = r2 / rs;
  }
}

// ---------------------------------------------------------------------------
// Scatter features into voxel-major acc (k,v,C). Wave per point, lane =
// channel. cnt==1 (98%): plain coalesced store. cnt>=2: row atomics.
// ---------------------------------------------------------------------------
__global__ __launch_bounds__(256) void scatter_feat_kernel(
    const float4* __restrict__ near4, const float4* __restrict__ far4,
    const float* __restrict__ fvT,
    const int* __restrict__ nn_idx, const float* __restrict__ nn_w,
    const float* __restrict__ cnt, float* __restrict__ acc) {
#pragma clang fp contract(off)
  int lane = threadIdx.x & 63;
  int wv = blockIdx.x * 4 + (threadIdx.x >> 6);  // global wave id = point slot
  int k = wv / (2 * N_);
  int p = wv % (2 * N_);
  bool is_far = p >= N_;
  int n = is_far ? p - N_ : p;

  float4 pt = is_far ? far4[k * N_ + n] : near4[k * N_ + n];
  int v = voxel_of(pt.x, pt.y, pt.w);
  if (v < 0) return;

  float val;
  if (!is_far) {
    val = fvT[((size_t)(k * N_ + n)) * C_ + lane];
  } else {
    int o = (k * N_ + n) * 3;
    int i0 = nn_idx[o], i1 = nn_idx[o + 1], i2 = nn_idx[o + 2];
    float w0 = nn_w[o], w1 = nn_w[o + 1], w2 = nn_w[o + 2];
    val = w0 * fvT[((size_t)(k * N_ + i0)) * C_ + lane]
        + w1 * fvT[((size_t)(k * N_ + i1)) * C_ + lane]
        + w2 * fvT[((size_t)(k * N_ + i2)) * C_ + lane];
  }
  size_t rowoff = ((size_t)k * NYNX_ + v) * C_;
  float cn = cnt[(size_t)k * NYNX_ + v];   // wave-uniform
  if (cn == 1.0f) acc[rowoff + lane] = val;
  else            atomicAdd(&acc[rowoff + lane], val);
}

// ---------------------------------------------------------------------------
// Emit out (B,C,NY,NX) from acc/cnt via LDS transpose. Per block: 64 voxels.
// Covers every out element exactly once (fuses the zero-fill + mean divide).
// ---------------------------------------------------------------------------
__global__ __launch_bounds__(256) void emit_kernel(
    const float* __restrict__ acc, const float* __restrict__ cnt,
    float* __restrict__ out) {
#pragma clang fp contract(off)
  __shared__ float tile[64][65];
  __shared__ float cs[64];
  int t = threadIdx.x;
  int k = blockIdx.y;
  int v0 = blockIdx.x * 64;

  if (t < 64) cs[t] = cnt[(size_t)k * NYNX_ + v0 + t];
  __syncthreads();

  const float4* acc4 = (const float4*)acc;
#pragma unroll
  for (int p = 0; p < 4; ++p) {
    int row = p * 16 + (t >> 4);     // voxel within block
    int f4  = t & 15;                // float4 within the 64-channel row
    float c = cs[row];
    float4 a = make_float4(0.0f, 0.0f, 0.0f, 0.0f);
    if (c > 0.0f) {
      a = acc4[((size_t)k * NYNX_ + v0 + row) * (C_ / 4) + f4];
      a.x /= c; a.y /= c; a.z /= c; a.w /= c;
    }
    tile[f4 * 4 + 0][row] = a.x;
    tile[f4 * 4 + 1][row] = a.y;
    tile[f4 * 4 + 2][row] = a.z;
    tile[f4 * 4 + 3][row] = a.w;
  }
  __syncthreads();

#pragma unroll
  for (int p = 0; p < 4; ++p) {
    int c  = p * 16 + (t >> 4);      // channel
    int xq = t & 15;                 // float4 of voxels
    float4 o = make_float4(tile[c][xq * 4 + 0], tile[c][xq * 4 + 1],
                           tile[c][xq * 4 + 2], tile[c][xq * 4 + 3]);
    ((float4*)out)[(((size_t)k * C_ + c) * NYNX_ + v0) / 4 + xq] = o;
  }
}

extern "C" void kernel_launch(void* const* d_in, const int* in_sizes, int n_in,
                              void* d_out, int out_size, void* d_ws, size_t ws_size,
                              hipStream_t stream) {
  const float* fv  = (const float*)d_in[0];  // (B,C,H,W)
  const float* pi  = (const float*)d_in[1];  // (B,4,H,W)
  const int*   pm  = (const int*)d_in[2];    // (B,H,W)
  const float* pif = (const float*)d_in[3];  // (B,4,H,W)
  const int*   pmf = (const int*)d_in[4];    // (B,H,W)
  float* out = (float*)d_out;                // (B,C,NY,NX) f32

  // workspace layout (16B aligned): small buffers < 8 MB, acc 134 MB at +8MB.
  char* wsb = (char*)d_ws;
  float*  fvT    = (float*)(wsb);                 // B*HW*C*4      = 4,194,304
  float*  cnt    = (float*)(wsb + 4194304);       // B*NYNX*4      = 2,097,152
  float4* near4  = (float4*)(wsb + 6291456);      // B*N*16        =   262,144
  float4* far4   = (float4*)(wsb + 6553600);      // B*N*16        =   262,144
  float4* nearnn = (float4*)(wsb + 6815744);      // B*N*16        =   262,144
  int*    nnidx  = (int*)(wsb + 7077888);         // B*N*3*4       =   196,608
  float*  nnw    = (float*)(wsb + 7274496);       // B*N*3*4       =   196,608
  int*    cstart = (int*)(wsb + 7471104);         // B*(1024+1)*4  =     8,320
  int*    gidx   = (int*)(wsb + 7479424);         // B*N*4         =    65,536
  float4* gpts   = (float4*)(wsb + 7544960);      // B*N*16        =   262,144
  float*  acc    = (float*)(wsb + 8388608);       // B*NYNX*C*4    = 134,217,728

  hipMemsetAsync(cnt, 0, (size_t)B_ * NYNX_ * sizeof(float), stream);

  prep_kernel<<<320, 256, 0, stream>>>(
      fv, pi, pm, pif, pmf, near4, far4, nearnn, cnt, fvT);
  build_grid_kernel<<<B_ + B_ * NYNX_ / 256, 256, 0, stream>>>(
      nearnn, cnt, cstart, gpts, gidx, acc);
  nn_search_kernel<<<B_ * N_ / 64, 256, 0, stream>>>(
      far4, cstart, gpts, gidx, nnidx, nnw);
  scatter_feat_kernel<<<B_ * 2 * N_ / 4, 256, 0, stream>>>(
      near4, far4, fvT, nnidx, nnw, cnt, acc);
  emit_kernel<<<dim3(NYNX_ / 64, B_), 256, 0, stream>>>(acc, cnt, out);
}

// Round 12
// 211.287 us; speedup vs baseline: 1.1267x; 1.0185x over previous
//
#include <hip/hip_runtime.h>
#include <math.h>

// Problem constants (match the jax reference)
constexpr int B_  = 2;
constexpr int C_  = 64;
constexpr int HW_ = 64 * 128;      // 8192
constexpr int N_  = HW_;           // points per image (near == far == 8192)
constexpr int NX_ = 512;
constexpr int NY_ = 512;
constexpr int NYNX_ = NX_ * NY_;   // 262144
constexpr int GC_  = 32;           // NN search grid is GC x GC cells of 1.6 m
constexpr int GCC_ = GC_ * GC_;    // 1024 cells
constexpr int LPF_ = 8;            // lanes per far point in nn_search
                                   // (R11: 4 lanes -> 256 blocks = 1 block/CU,
                                   //  latency-bound; 8 -> 512 blocks = 2/CU)

// ---------------------------------------------------------------------------
// Shared voxel binning (numpy f32 bitwise). -1 = contributes nothing.
// ---------------------------------------------------------------------------
__device__ __forceinline__ int voxel_of(float x, float y, float w) {
#pragma clang fp contract(off)
  if (w == 0.0f) return -1;
  float qx = (x - 0.0f) / 0.1f;
  float qy = (y - (-25.6f)) / 0.1f;
  int ix = (int)floorf(qx);
  int iy = (int)floorf(qy);
  if (ix < 0 || ix >= NX_ || iy < 0 || iy >= NY_) return -1;
  return iy * NX_ + ix;
}

// NN-grid cell coords (internal only — must be identical in build & search).
__device__ __forceinline__ int gcell_x(float x) {
  int c = (int)floorf(x * 0.625f);          // /1.6
  return min(GC_ - 1, max(0, c));
}
__device__ __forceinline__ int gcell_y(float y) {
  int c = (int)floorf((y + 25.6f) * 0.625f);
  return min(GC_ - 1, max(0, c));
}

// ---------------------------------------------------------------------------
// Fused prep: blocks [0,64) pack+count points; blocks [64,320) transpose
// fv (B,C,HW) -> fvT (B,HW,C). The two halves are independent.
// ---------------------------------------------------------------------------
__global__ __launch_bounds__(256) void prep_kernel(
    const float* __restrict__ fv,
    const float* __restrict__ pi, const int* __restrict__ pm,
    const float* __restrict__ pif, const int* __restrict__ pmf,
    float4* __restrict__ near4, float4* __restrict__ far4,
    float4* __restrict__ nearnn, float* __restrict__ cnt,
    float* __restrict__ fvT) {
#pragma clang fp contract(off)
  __shared__ float tile[64][65];
  if (blockIdx.x < 64) {
    // ---- pack + count ----
    int t = blockIdx.x * 256 + threadIdx.x;        // over B_*N_
    int k = t / N_, n = t % N_;
    const float* base  = pi  + (size_t)k * 4 * HW_;
    const float* basef = pif + (size_t)k * 4 * HW_;
    float x = base[n], y = base[HW_ + n], z = base[2 * HW_ + n];
    bool v = pm[k * HW_ + n] > 0;
    near4[t] = make_float4(x, y, z, v ? 1.0f : 0.0f);
    float sq = (x * x + y * y) + z * z;   // numpy 3-elem sum order
    nearnn[t] = v ? make_float4(x, y, z, sq)
                 : make_float4(0.0f, 0.0f, 0.0f, 1e10f);
    float fx = basef[n], fy = basef[HW_ + n], fz = basef[2 * HW_ + n];
    bool vf = pmf[k * HW_ + n] > 0;
    far4[t] = make_float4(fx, fy, fz, vf ? 1.0f : 0.0f);

    int vn = voxel_of(x, y, v ? 1.0f : 0.0f);
    if (vn >= 0) atomicAdd(&cnt[(size_t)k * NYNX_ + vn], 1.0f);
    int vfv = voxel_of(fx, fy, vf ? 1.0f : 0.0f);
    if (vfv >= 0) atomicAdd(&cnt[(size_t)k * NYNX_ + vfv], 1.0f);
  } else {
    // ---- transpose ----
    int bid = blockIdx.x - 64;          // 0..255
    int k = bid >> 7;                   // /128
    int n0 = (bid & 127) * 64;
    int tx = threadIdx.x & 63, ty = threadIdx.x >> 6;
    for (int c = ty; c < C_; c += 4)
      tile[c][tx] = fv[((size_t)(k * C_ + c)) * HW_ + n0 + tx];
    __syncthreads();
    for (int nn = ty; nn < 64; nn += 4)
      fvT[((size_t)(k * HW_ + n0 + nn)) * C_ + tx] = tile[tx][nn];
  }
}

// ---------------------------------------------------------------------------
// Lexicographic stable top-3 insert on (value, index): lower value wins,
// ties broken by lower index. Order-INDEPENDENT (safe for arbitrary candidate
// order) and equal to jax stable top-k. Invariant: slots lex-sorted.
// ---------------------------------------------------------------------------
__device__ __forceinline__ void merge3L(float tv, int idx,
                                        float& b0, float& b1, float& b2,
                                        int& i0, int& i1, int& i2) {
  bool w0 = (tv < b0) || (tv == b0 && idx < i0);
  bool w1 = (tv < b1) || (tv == b1 && idx < i1);
  bool w2 = (tv < b2) || (tv == b2 && idx < i2);
  float ob0 = b0, ob1 = b1;
  int   oi0 = i0, oi1 = i1;
  b0 = w0 ? tv : b0;                    i0 = w0 ? idx : i0;
  b1 = w0 ? ob0 : (w1 ? tv : b1);       i1 = w0 ? oi0 : (w1 ? idx : i1);
  b2 = w1 ? ob1 : (w2 ? tv : b2);       i2 = w1 ? oi1 : (w2 ? idx : i2);
}

// ---------------------------------------------------------------------------
// build_grid: blocks [0,B_) bin VALID near points into the 32x32 cell grid
// (LDS count -> LDS scan -> global CSR + LDS-cursor fill). Within-cell order
// is arbitrary (atomic) — harmless, selection is lexicographic.
// Blocks [B_, B_+2048): zero acc rows where cnt>=2 (~130 voxels/batch).
// ---------------------------------------------------------------------------
__global__ __launch_bounds__(256) void build_grid_kernel(
    const float4* __restrict__ nearnn, const float* __restrict__ cnt,
    int* __restrict__ cell_start, float4* __restrict__ gpts,
    int* __restrict__ gidx, float* __restrict__ acc) {
  __shared__ int lcnt[GCC_];
  __shared__ int lsum[256];
  __shared__ int lcur[GCC_];
  int t = threadIdx.x;
  if (blockIdx.x < (unsigned)B_) {
    int k = blockIdx.x;
    for (int i = t; i < GCC_; i += 256) lcnt[i] = 0;
    __syncthreads();
    for (int n = t; n < N_; n += 256) {
      float4 q = nearnn[k * N_ + n];
      if (q.w < 1e9f)
        atomicAdd(&lcnt[gcell_y(q.y) * GC_ + gcell_x(q.x)], 1);
    }
    __syncthreads();
    // scan: per-thread 4-elem serial + Hillis-Steele over 256 partials
    int base = t * 4;
    int c0 = lcnt[base], c1 = lcnt[base + 1], c2 = lcnt[base + 2], c3 = lcnt[base + 3];
    int s = c0 + c1 + c2 + c3;
    lsum[t] = s;
    __syncthreads();
    for (int off = 1; off < 256; off <<= 1) {
      int v = (t >= off) ? lsum[t - off] : 0;
      __syncthreads();
      lsum[t] += v;
      __syncthreads();
    }
    int ex = lsum[t] - s;                 // exclusive prefix of this thread's 4
    lcnt[base] = ex;
    lcnt[base + 1] = ex + c0;
    lcnt[base + 2] = ex + c0 + c1;
    lcnt[base + 3] = ex + c0 + c1 + c2;
    __syncthreads();
    for (int i = t; i < GCC_; i += 256) {
      cell_start[k * (GCC_ + 1) + i] = lcnt[i];
      lcur[i] = lcnt[i];
    }
    if (t == 255) cell_start[k * (GCC_ + 1) + GCC_] = lsum[255];
    __syncthreads();
    // fill
    for (int n = t; n < N_; n += 256) {
      float4 q = nearnn[k * N_ + n];
      if (q.w < 1e9f) {
        int c = gcell_y(q.y) * GC_ + gcell_x(q.x);
        int p = atomicAdd(&lcur[c], 1);
        gpts[k * N_ + p] = q;
        gidx[k * N_ + p] = n;
      }
    }
  } else {
    int tt = (blockIdx.x - B_) * 256 + t;   // over B_*NYNX_
    if (cnt[tt] >= 2.0f) {
      float4* row = (float4*)(acc + (size_t)tt * C_);
      float4 z = make_float4(0.0f, 0.0f, 0.0f, 0.0f);
      for (int i = 0; i < C_ / 4; ++i) row[i] = z;
    }
  }
}

// ---------------------------------------------------------------------------
// nn_search: exact 3-NN via expanding Chebyshev rings over the cell grid.
// LPF_=8 lanes cooperate per far point (lane q takes ring-cells i%8==q):
// 512 blocks = 2 blocks/CU = 8 waves/CU for latency hiding (R11 had 1/CU).
// Every candidate scored with the bitwise reference f32 formula; stable
// lexicographic top-3 (order-independent). Stop bound: after ring r, any
// unvisited point has true-d2 >= (r*1.6)^2 and formula-d2 >= true-d2-~2e-3,
// so (r*1.6)^2 > octet_min(b2) + 0.01 can never exclude a winner (any lane's
// subset 3rd-best >= union 3rd-best, so the min is a valid upper bound).
// ---------------------------------------------------------------------------
__global__ __launch_bounds__(256) void nn_search_kernel(
    const float4* __restrict__ far4, const int* __restrict__ cell_start,
    const float4* __restrict__ gpts, const int* __restrict__ gidx,
    int* __restrict__ nn_idx, float* __restrict__ nn_w) {
#pragma clang fp contract(off)
  int tid = threadIdx.x;
  int q = tid & (LPF_ - 1);
  int g = blockIdx.x * (256 / LPF_) + (tid / LPF_);   // far point id over BN
  int k = g >> 13;                        // /8192
  int m = g & (N_ - 1);

  float4 f = far4[k * N_ + m];
  float sf = (f.x * f.x + f.y * f.y) + f.z * f.z;   // numpy 3-elem order
  float ax = 2.0f * f.x, ay = 2.0f * f.y, az = 2.0f * f.z;
  int fcx = gcell_x(f.x), fcy = gcell_y(f.y);
  const int* cs_ = cell_start + k * (GCC_ + 1);

  float b0 = 1e30f, b1 = 1e30f, b2 = 1e30f;
  int i0 = 0, i1 = 0, i2 = 0;

  for (int r = 0; r < GC_; ++r) {
    int nc = (r == 0) ? 1 : 8 * r;
    for (int i = q; i < nc; i += LPF_) {
      int dx, dy;
      if (r == 0)            { dx = 0;             dy = 0; }
      else if (i < 2*r + 1)  { dx = i - r;         dy = -r; }
      else if (i < 4*r + 2)  { dx = i - (3*r + 1); dy = r; }
      else if (i < 6*r + 1)  { dx = -r;            dy = i - (5*r + 1); }
      else                   { dx = r;             dy = i - 7*r; }
      int cx = fcx + dx, cy = fcy + dy;
      if (cx < 0 || cx >= GC_ || cy < 0 || cy >= GC_) continue;
      int c = cy * GC_ + cx;
      int s = cs_[c], e = cs_[c + 1];
      for (int j = s; j < e; ++j) {
        float4 p = gpts[k * N_ + j];
        int idx = gidx[k * N_ + j];
        float p0 = ax * p.x;                                  // round(ax*px)
        float mm = __builtin_fmaf(az, p.z, __builtin_fmaf(ay, p.y, p0));
        float tv = (sf + p.w) - mm;
        merge3L(tv, idx, b0, b1, b2, i0, i1, i2);
      }
    }
    // octet-shared conservative bound (min of lanes' 3rd-best; 1e30 until
    // some lane holds 3 -> keep expanding, always safe)
    float s2 = b2;
    s2 = fminf(s2, __shfl_xor(s2, 1));
    s2 = fminf(s2, __shfl_xor(s2, 2));
    s2 = fminf(s2, __shfl_xor(s2, 4));
    float rd = (float)r * 1.6f;
    if (rd * rd > s2 + 0.01f) break;
  }

  // octet merge: lane 0 folds lanes 1..7 (lexicographic, order-independent)
  int base = tid & ~(LPF_ - 1);
  for (int s = 1; s < LPF_; ++s) {
    float v0 = __shfl(b0, base + s), v1 = __shfl(b1, base + s), v2 = __shfl(b2, base + s);
    int   j0 = __shfl(i0, base + s), j1 = __shfl(i1, base + s), j2 = __shfl(i2, base + s);
    if (q == 0) {
      merge3L(v0, j0, b0, b1, b2, i0, i1, i2);
      merge3L(v1, j1, b0, b1, b2, i0, i1, i2);
      merge3L(v2, j2, b0, b1, b2, i0, i1, i2);
    }
  }
  if (q == 0) {
    float r0 = 1.0f / (b0 + 1e-8f);
    float r1 = 1.0f / (b1 + 1e-8f);
    float r2 = 1.0f / (b2 + 1e-8f);
    float rs = (r0 + r1) + r2;
    int o = g * 3;
    nn_idx[o] = i0; nn_idx[o + 1] = i1; nn_idx[o + 2] = i2;
    nn_w[o] = r0 / rs; nn_w[o + 1] = r1 / rs; nn_w[o + 2] = r2 / rs;
  }
}

// ---------------------------------------------------------------------------
// Scatter features into voxel-major acc (k,v,C). Wave per point, lane =
// channel. cnt==1 (98%): plain coalesced store. cnt>=2: row atomics.
// ---------------------------------------------------------------------------
__global__ __launch_bounds__(256) void scatter_feat_kernel(
    const float4* __restrict__ near4, const float4* __restrict__ far4,
    const float* __restrict__ fvT,
    const int* __restrict__ nn_idx, const float* __restrict__ nn_w,
    const float* __restrict__ cnt, float* __restrict__ acc) {
#pragma clang fp contract(off)
  int lane = threadIdx.x & 63;
  int wv = blockIdx.x * 4 + (threadIdx.x >> 6);  // global wave id = point slot
  int k = wv / (2 * N_);
  int p = wv % (2 * N_);
  bool is_far = p >= N_;
  int n = is_far ? p - N_ : p;

  float4 pt = is_far ? far4[k * N_ + n] : near4[k * N_ + n];
  int v = voxel_of(pt.x, pt.y, pt.w);
  if (v < 0) return;

  float val;
  if (!is_far) {
    val = fvT[((size_t)(k * N_ + n)) * C_ + lane];
  } else {
    int o = (k * N_ + n) * 3;
    int i0 = nn_idx[o], i1 = nn_idx[o + 1], i2 = nn_idx[o + 2];
    float w0 = nn_w[o], w1 = nn_w[o + 1], w2 = nn_w[o + 2];
    val = w0 * fvT[((size_t)(k * N_ + i0)) * C_ + lane]
        + w1 * fvT[((size_t)(k * N_ + i1)) * C_ + lane]
        + w2 * fvT[((size_t)(k * N_ + i2)) * C_ + lane];
  }
  size_t rowoff = ((size_t)k * NYNX_ + v) * C_;
  float cn = cnt[(size_t)k * NYNX_ + v];   // wave-uniform
  if (cn == 1.0f) acc[rowoff + lane] = val;
  else            atomicAdd(&acc[rowoff + lane], val);
}

// ---------------------------------------------------------------------------
// Emit out (B,C,NY,NX) from acc/cnt via LDS transpose. Per block: 64 voxels.
// Covers every out element exactly once (fuses the zero-fill + mean divide).
// ---------------------------------------------------------------------------
__global__ __launch_bounds__(256) void emit_kernel(
    const float* __restrict__ acc, const float* __restrict__ cnt,
    float* __restrict__ out) {
#pragma clang fp contract(off)
  __shared__ float tile[64][65];
  __shared__ float cs[64];
  int t = threadIdx.x;
  int k = blockIdx.y;
  int v0 = blockIdx.x * 64;

  if (t < 64) cs[t] = cnt[(size_t)k * NYNX_ + v0 + t];
  __syncthreads();

  const float4* acc4 = (const float4*)acc;
#pragma unroll
  for (int p = 0; p < 4; ++p) {
    int row = p * 16 + (t >> 4);     // voxel within block
    int f4  = t & 15;                // float4 within the 64-channel row
    float c = cs[row];
    float4 a = make_float4(0.0f, 0.0f, 0.0f, 0.0f);
    if (c > 0.0f) {
      a = acc4[((size_t)k * NYNX_ + v0 + row) * (C_ / 4) + f4];
      a.x /= c; a.y /= c; a.z /= c; a.w /= c;
    }
    tile[f4 * 4 + 0][row] = a.x;
    tile[f4 * 4 + 1][row] = a.y;
    tile[f4 * 4 + 2][row] = a.z;
    tile[f4 * 4 + 3][row] = a.w;
  }
  __syncthreads();

#pragma unroll
  for (int p = 0; p < 4; ++p) {
    int c  = p * 16 + (t >> 4);      // channel
    int xq = t & 15;                 // float4 of voxels
    float4 o = make_float4(tile[c][xq * 4 + 0], tile[c][xq * 4 + 1],
                           tile[c][xq * 4 + 2], tile[c][xq * 4 + 3]);
    ((float4*)out)[(((size_t)k * C_ + c) * NYNX_ + v0) / 4 + xq] = o;
  }
}

extern "C" void kernel_launch(void* const* d_in, const int* in_sizes, int n_in,
                              void* d_out, int out_size, void* d_ws, size_t ws_size,
                              hipStream_t stream) {
  const float* fv  = (const float*)d_in[0];  // (B,C,H,W)
  const float* pi  = (const float*)d_in[1];  // (B,4,H,W)
  const int*   pm  = (const int*)d_in[2];    // (B,H,W)
  const float* pif = (const float*)d_in[3];  // (B,4,H,W)
  const int*   pmf = (const int*)d_in[4];    // (B,H,W)
  float* out = (float*)d_out;                // (B,C,NY,NX) f32

  // workspace layout (16B aligned): small buffers < 8 MB, acc 134 MB at +8MB.
  char* wsb = (char*)d_ws;
  float*  fvT    = (float*)(wsb);                 // B*HW*C*4      = 4,194,304
  float*  cnt    = (float*)(wsb + 4194304);       // B*NYNX*4      = 2,097,152
  float4* near4  = (float4*)(wsb + 6291456);      // B*N*16        =   262,144
  float4* far4   = (float4*)(wsb + 6553600);      // B*N*16        =   262,144
  float4* nearnn = (float4*)(wsb + 6815744);      // B*N*16        =   262,144
  int*    nnidx  = (int*)(wsb + 7077888);         // B*N*3*4       =   196,608
  float*  nnw    = (float*)(wsb + 7274496);       // B*N*3*4       =   196,608
  int*    cstart = (int*)(wsb + 7471104);         // B*(1024+1)*4  =     8,320
  int*    gidx   = (int*)(wsb + 7479424);         // B*N*4         =    65,536
  float4* gpts   = (float4*)(wsb + 7544960);      // B*N*16        =   262,144
  float*  acc    = (float*)(wsb + 8388608);       // B*NYNX*C*4    = 134,217,728

  hipMemsetAsync(cnt, 0, (size_t)B_ * NYNX_ * sizeof(float), stream);

  prep_kernel<<<320, 256, 0, stream>>>(
      fv, pi, pm, pif, pmf, near4, far4, nearnn, cnt, fvT);
  build_grid_kernel<<<B_ + B_ * NYNX_ / 256, 256, 0, stream>>>(
      nearnn, cnt, cstart, gpts, gidx, acc);
  nn_search_kernel<<<B_ * N_ * LPF_ / 256, 256, 0, stream>>>(
      far4, cstart, gpts, gidx, nnidx, nnw);
  scatter_feat_kernel<<<B_ * 2 * N_ / 4, 256, 0, stream>>>(
      near4, far4, fvT, nnidx, nnw, cnt, acc);
  emit_kernel<<<dim3(NYNX_ / 64, B_), 256, 0, stream>>>(acc, cnt, out);
}

// Round 13
// 204.348 us; speedup vs baseline: 1.1650x; 1.0340x over previous
//
#include <hip/hip_runtime.h>
#include <math.h>

// Problem constants (match the jax reference)
constexpr int B_  = 2;
constexpr int C_  = 64;
constexpr int HW_ = 64 * 128;      // 8192
constexpr int N_  = HW_;           // points per image (near == far == 8192)
constexpr int NX_ = 512;
constexpr int NY_ = 512;
constexpr int NYNX_ = NX_ * NY_;   // 262144
constexpr int GC_  = 32;           // NN search grid is GC x GC cells of 1.6 m
constexpr int GCC_ = GC_ * GC_;    // 1024 cells
constexpr int LPF_ = 8;            // lanes per far point in nn_search
constexpr int BN_  = B_ * N_;      // 16384
constexpr int NNB_ = BN_ / (256 / LPF_);   // 512 NN blocks (32 far pts/block)

// ---------------------------------------------------------------------------
// Shared voxel binning (numpy f32 bitwise). -1 = contributes nothing.
// ---------------------------------------------------------------------------
__device__ __forceinline__ int voxel_of(float x, float y, float w) {
#pragma clang fp contract(off)
  if (w == 0.0f) return -1;
  float qx = (x - 0.0f) / 0.1f;
  float qy = (y - (-25.6f)) / 0.1f;
  int ix = (int)floorf(qx);
  int iy = (int)floorf(qy);
  if (ix < 0 || ix >= NX_ || iy < 0 || iy >= NY_) return -1;
  return iy * NX_ + ix;
}

// NN-grid cell coords (internal only — must be identical in build & search).
__device__ __forceinline__ int gcell_x(float x) {
  int c = (int)floorf(x * 0.625f);          // /1.6
  return min(GC_ - 1, max(0, c));
}
__device__ __forceinline__ int gcell_y(float y) {
  int c = (int)floorf((y + 25.6f) * 0.625f);
  return min(GC_ - 1, max(0, c));
}

// ---------------------------------------------------------------------------
// Fused prep: blocks [0,64) pack+count points; blocks [64,320) transpose
// fv (B,C,HW) -> fvT (B,HW,C). The two halves are independent.
// ---------------------------------------------------------------------------
__global__ __launch_bounds__(256) void prep_kernel(
    const float* __restrict__ fv,
    const float* __restrict__ pi, const int* __restrict__ pm,
    const float* __restrict__ pif, const int* __restrict__ pmf,
    float4* __restrict__ near4, float4* __restrict__ far4,
    float4* __restrict__ nearnn, float* __restrict__ cnt,
    float* __restrict__ fvT) {
#pragma clang fp contract(off)
  __shared__ float tile[64][65];
  if (blockIdx.x < 64) {
    // ---- pack + count ----
    int t = blockIdx.x * 256 + threadIdx.x;        // over B_*N_
    int k = t / N_, n = t % N_;
    const float* base  = pi  + (size_t)k * 4 * HW_;
    const float* basef = pif + (size_t)k * 4 * HW_;
    float x = base[n], y = base[HW_ + n], z = base[2 * HW_ + n];
    bool v = pm[k * HW_ + n] > 0;
    near4[t] = make_float4(x, y, z, v ? 1.0f : 0.0f);
    float sq = (x * x + y * y) + z * z;   // numpy 3-elem sum order
    nearnn[t] = v ? make_float4(x, y, z, sq)
                 : make_float4(0.0f, 0.0f, 0.0f, 1e10f);
    float fx = basef[n], fy = basef[HW_ + n], fz = basef[2 * HW_ + n];
    bool vf = pmf[k * HW_ + n] > 0;
    far4[t] = make_float4(fx, fy, fz, vf ? 1.0f : 0.0f);

    int vn = voxel_of(x, y, v ? 1.0f : 0.0f);
    if (vn >= 0) atomicAdd(&cnt[(size_t)k * NYNX_ + vn], 1.0f);
    int vfv = voxel_of(fx, fy, vf ? 1.0f : 0.0f);
    if (vfv >= 0) atomicAdd(&cnt[(size_t)k * NYNX_ + vfv], 1.0f);
  } else {
    // ---- transpose ----
    int bid = blockIdx.x - 64;          // 0..255
    int k = bid >> 7;                   // /128
    int n0 = (bid & 127) * 64;
    int tx = threadIdx.x & 63, ty = threadIdx.x >> 6;
    for (int c = ty; c < C_; c += 4)
      tile[c][tx] = fv[((size_t)(k * C_ + c)) * HW_ + n0 + tx];
    __syncthreads();
    for (int nn = ty; nn < 64; nn += 4)
      fvT[((size_t)(k * HW_ + n0 + nn)) * C_ + tx] = tile[tx][nn];
  }
}

// ---------------------------------------------------------------------------
// Lexicographic stable top-3 insert on (value, index): lower value wins,
// ties broken by lower index. Order-INDEPENDENT (safe for arbitrary candidate
// order) and equal to jax stable top-k. Invariant: slots lex-sorted.
// ---------------------------------------------------------------------------
__device__ __forceinline__ void merge3L(float tv, int idx,
                                        float& b0, float& b1, float& b2,
                                        int& i0, int& i1, int& i2) {
  bool w0 = (tv < b0) || (tv == b0 && idx < i0);
  bool w1 = (tv < b1) || (tv == b1 && idx < i1);
  bool w2 = (tv < b2) || (tv == b2 && idx < i2);
  float ob0 = b0, ob1 = b1;
  int   oi0 = i0, oi1 = i1;
  b0 = w0 ? tv : b0;                    i0 = w0 ? idx : i0;
  b1 = w0 ? ob0 : (w1 ? tv : b1);       i1 = w0 ? oi0 : (w1 ? idx : i1);
  b2 = w1 ? ob1 : (w2 ? tv : b2);       i2 = w1 ? oi1 : (w2 ? idx : i2);
}

// ---------------------------------------------------------------------------
// build_grid: blocks [0,B_) bin VALID near points into the 32x32 cell grid
// (LDS count -> LDS scan -> global CSR + LDS-cursor fill). Within-cell order
// is arbitrary (atomic) — harmless, selection is lexicographic.
// Blocks [B_, B_+2048): zero acc rows where cnt>=2 (~130 voxels/batch).
// ---------------------------------------------------------------------------
__global__ __launch_bounds__(256) void build_grid_kernel(
    const float4* __restrict__ nearnn, const float* __restrict__ cnt,
    int* __restrict__ cell_start, float4* __restrict__ gpts,
    int* __restrict__ gidx, float* __restrict__ acc) {
  __shared__ int lcnt[GCC_];
  __shared__ int lsum[256];
  __shared__ int lcur[GCC_];
  int t = threadIdx.x;
  if (blockIdx.x < (unsigned)B_) {
    int k = blockIdx.x;
    for (int i = t; i < GCC_; i += 256) lcnt[i] = 0;
    __syncthreads();
    for (int n = t; n < N_; n += 256) {
      float4 q = nearnn[k * N_ + n];
      if (q.w < 1e9f)
        atomicAdd(&lcnt[gcell_y(q.y) * GC_ + gcell_x(q.x)], 1);
    }
    __syncthreads();
    // scan: per-thread 4-elem serial + Hillis-Steele over 256 partials
    int base = t * 4;
    int c0 = lcnt[base], c1 = lcnt[base + 1], c2 = lcnt[base + 2], c3 = lcnt[base + 3];
    int s = c0 + c1 + c2 + c3;
    lsum[t] = s;
    __syncthreads();
    for (int off = 1; off < 256; off <<= 1) {
      int v = (t >= off) ? lsum[t - off] : 0;
      __syncthreads();
      lsum[t] += v;
      __syncthreads();
    }
    int ex = lsum[t] - s;                 // exclusive prefix of this thread's 4
    lcnt[base] = ex;
    lcnt[base + 1] = ex + c0;
    lcnt[base + 2] = ex + c0 + c1;
    lcnt[base + 3] = ex + c0 + c1 + c2;
    __syncthreads();
    for (int i = t; i < GCC_; i += 256) {
      cell_start[k * (GCC_ + 1) + i] = lcnt[i];
      lcur[i] = lcnt[i];
    }
    if (t == 255) cell_start[k * (GCC_ + 1) + GCC_] = lsum[255];
    __syncthreads();
    // fill
    for (int n = t; n < N_; n += 256) {
      float4 q = nearnn[k * N_ + n];
      if (q.w < 1e9f) {
        int c = gcell_y(q.y) * GC_ + gcell_x(q.x);
        int p = atomicAdd(&lcur[c], 1);
        gpts[k * N_ + p] = q;
        gidx[k * N_ + p] = n;
      }
    }
  } else {
    int tt = (blockIdx.x - B_) * 256 + t;   // over B_*NYNX_
    if (cnt[tt] >= 2.0f) {
      float4* row = (float4*)(acc + (size_t)tt * C_);
      float4 z = make_float4(0.0f, 0.0f, 0.0f, 0.0f);
      for (int i = 0; i < C_ / 4; ++i) row[i] = z;
    }
  }
}

// ---------------------------------------------------------------------------
// Fused NN + scatter.
// Blocks [0, NNB_): exact 3-NN (expanding Chebyshev rings, 8 lanes/far) then
// the SAME octet gathers the three fvT rows (float4, coalesced) and writes
// the interpolated acc row — no nn_idx/nn_w global roundtrip ((i,w) broadcast
// in-register via shfl, bit-exact f32). Value expr identical to R12 scatter:
// (w0*a + w1*b) + w2*c, contract off.
// Blocks [NNB_, NNB_+4096): near-point scatter, wave/point, lane = channel.
// Both halves only need prep+build_grid (cnt final, collision rows zeroed).
// cnt==1 rows (98%) are plain stores (single writer); cnt>=2 rows atomics.
// ---------------------------------------------------------------------------
__global__ __launch_bounds__(256) void nn_scatter_kernel(
    const float4* __restrict__ far4, const int* __restrict__ cell_start,
    const float4* __restrict__ gpts, const int* __restrict__ gidx,
    const float4* __restrict__ near4, const float* __restrict__ fvT,
    const float* __restrict__ cnt, float* __restrict__ acc) {
#pragma clang fp contract(off)
  int tid = threadIdx.x;
  if (blockIdx.x < (unsigned)NNB_) {
    int q = tid & (LPF_ - 1);
    int g = blockIdx.x * (256 / LPF_) + (tid / LPF_);   // far point id over BN
    int k = g >> 13;                        // /8192
    int m = g & (N_ - 1);

    float4 f = far4[k * N_ + m];
    float sf = (f.x * f.x + f.y * f.y) + f.z * f.z;   // numpy 3-elem order
    float ax = 2.0f * f.x, ay = 2.0f * f.y, az = 2.0f * f.z;
    int fcx = gcell_x(f.x), fcy = gcell_y(f.y);
    const int* cs_ = cell_start + k * (GCC_ + 1);

    float b0 = 1e30f, b1 = 1e30f, b2 = 1e30f;
    int i0 = 0, i1 = 0, i2 = 0;

    for (int r = 0; r < GC_; ++r) {
      int nc = (r == 0) ? 1 : 8 * r;
      for (int i = q; i < nc; i += LPF_) {
        int dx, dy;
        if (r == 0)            { dx = 0;             dy = 0; }
        else if (i < 2*r + 1)  { dx = i - r;         dy = -r; }
        else if (i < 4*r + 2)  { dx = i - (3*r + 1); dy = r; }
        else if (i < 6*r + 1)  { dx = -r;            dy = i - (5*r + 1); }
        else                   { dx = r;             dy = i - 7*r; }
        int cx = fcx + dx, cy = fcy + dy;
        if (cx < 0 || cx >= GC_ || cy < 0 || cy >= GC_) continue;
        int c = cy * GC_ + cx;
        int s = cs_[c], e = cs_[c + 1];
        for (int j = s; j < e; ++j) {
          float4 p = gpts[k * N_ + j];
          int idx = gidx[k * N_ + j];
          float p0 = ax * p.x;                                  // round(ax*px)
          float mm = __builtin_fmaf(az, p.z, __builtin_fmaf(ay, p.y, p0));
          float tv = (sf + p.w) - mm;
          merge3L(tv, idx, b0, b1, b2, i0, i1, i2);
        }
      }
      // octet-shared conservative bound (min of lanes' 3rd-best; 1e30 until
      // some lane holds 3 -> keep expanding, always safe)
      float s2 = b2;
      s2 = fminf(s2, __shfl_xor(s2, 1));
      s2 = fminf(s2, __shfl_xor(s2, 2));
      s2 = fminf(s2, __shfl_xor(s2, 4));
      float rd = (float)r * 1.6f;
      if (rd * rd > s2 + 0.01f) break;
    }

    // octet merge on lane 0 (lexicographic, order-independent)
    int base = tid & ~(LPF_ - 1);
    for (int s = 1; s < LPF_; ++s) {
      float v0 = __shfl(b0, base + s), v1 = __shfl(b1, base + s), v2 = __shfl(b2, base + s);
      int   j0 = __shfl(i0, base + s), j1 = __shfl(i1, base + s), j2 = __shfl(i2, base + s);
      if (q == 0) {
        merge3L(v0, j0, b0, b1, b2, i0, i1, i2);
        merge3L(v1, j1, b0, b1, b2, i0, i1, i2);
        merge3L(v2, j2, b0, b1, b2, i0, i1, i2);
      }
    }
    // weights on lane 0 (exactly as reference), then broadcast bit-exact
    float w0_ = 0.0f, w1_ = 0.0f, w2_ = 0.0f;
    if (q == 0) {
      float r0 = 1.0f / (b0 + 1e-8f);
      float r1 = 1.0f / (b1 + 1e-8f);
      float r2 = 1.0f / (b2 + 1e-8f);
      float rs = (r0 + r1) + r2;
      w0_ = r0 / rs; w1_ = r1 / rs; w2_ = r2 / rs;
    }
    float w0 = __shfl(w0_, base), w1 = __shfl(w1_, base), w2 = __shfl(w2_, base);
    int   j0 = __shfl(i0, base),  j1 = __shfl(i1, base),  j2 = __shfl(i2, base);

    // far-point scatter: octet handles the 64-channel row, lane q owns
    // float4 chunks {2q, 2q+1} (coalesced 256 B per row).
    int v = voxel_of(f.x, f.y, f.w);
    if (v < 0) return;
    float cn = cnt[(size_t)k * NYNX_ + v];
    const float4* r0p = (const float4*)(fvT + ((size_t)(k * N_ + j0)) * C_);
    const float4* r1p = (const float4*)(fvT + ((size_t)(k * N_ + j1)) * C_);
    const float4* r2p = (const float4*)(fvT + ((size_t)(k * N_ + j2)) * C_);
    size_t rowoff = ((size_t)k * NYNX_ + v) * C_;
#pragma unroll
    for (int h = 0; h < 2; ++h) {
      int c4 = q * 2 + h;
      float4 a = r0p[c4], b = r1p[c4], c = r2p[c4];
      float4 val;
      val.x = (w0 * a.x + w1 * b.x) + w2 * c.x;
      val.y = (w0 * a.y + w1 * b.y) + w2 * c.y;
      val.z = (w0 * a.z + w1 * b.z) + w2 * c.z;
      val.w = (w0 * a.w + w1 * b.w) + w2 * c.w;
      if (cn == 1.0f) {
        ((float4*)(acc + rowoff))[c4] = val;
      } else {
        float* p = acc + rowoff + c4 * 4;
        atomicAdd(p + 0, val.x); atomicAdd(p + 1, val.y);
        atomicAdd(p + 2, val.z); atomicAdd(p + 3, val.w);
      }
    }
  } else {
    // ---- near-point scatter: wave per point, lane = channel ----
    int lane = tid & 63;
    int wv = (blockIdx.x - NNB_) * 4 + (tid >> 6);  // 0..BN_-1
    int k = wv >> 13;
    int n = wv & (N_ - 1);
    float4 pt = near4[k * N_ + n];
    int v = voxel_of(pt.x, pt.y, pt.w);
    if (v < 0) return;
    float val = fvT[((size_t)(k * N_ + n)) * C_ + lane];
    size_t rowoff = ((size_t)k * NYNX_ + v) * C_;
    float cn = cnt[(size_t)k * NYNX_ + v];   // wave-uniform
    if (cn == 1.0f) acc[rowoff + lane] = val;
    else            atomicAdd(&acc[rowoff + lane], val);
  }
}

// ---------------------------------------------------------------------------
// Emit out (B,C,NY,NX) from acc/cnt via LDS transpose. Per block: 64 voxels.
// Covers every out element exactly once (fuses the zero-fill + mean divide).
// ---------------------------------------------------------------------------
__global__ __launch_bounds__(256) void emit_kernel(
    const float* __restrict__ acc, const float* __restrict__ cnt,
    float* __restrict__ out) {
#pragma clang fp contract(off)
  __shared__ float tile[64][65];
  __shared__ float cs[64];
  int t = threadIdx.x;
  int k = blockIdx.y;
  int v0 = blockIdx.x * 64;

  if (t < 64) cs[t] = cnt[(size_t)k * NYNX_ + v0 + t];
  __syncthreads();

  const float4* acc4 = (const float4*)acc;
#pragma unroll
  for (int p = 0; p < 4; ++p) {
    int row = p * 16 + (t >> 4);     // voxel within block
    int f4  = t & 15;                // float4 within the 64-channel row
    float c = cs[row];
    float4 a = make_float4(0.0f, 0.0f, 0.0f, 0.0f);
    if (c > 0.0f) {
      a = acc4[((size_t)k * NYNX_ + v0 + row) * (C_ / 4) + f4];
      a.x /= c; a.y /= c; a.z /= c; a.w /= c;
    }
    tile[f4 * 4 + 0][row] = a.x;
    tile[f4 * 4 + 1][row] = a.y;
    tile[f4 * 4 + 2][row] = a.z;
    tile[f4 * 4 + 3][row] = a.w;
  }
  __syncthreads();

#pragma unroll
  for (int p = 0; p < 4; ++p) {
    int c  = p * 16 + (t >> 4);      // channel
    int xq = t & 15;                 // float4 of voxels
    float4 o = make_float4(tile[c][xq * 4 + 0], tile[c][xq * 4 + 1],
                           tile[c][xq * 4 + 2], tile[c][xq * 4 + 3]);
    ((float4*)out)[(((size_t)k * C_ + c) * NYNX_ + v0) / 4 + xq] = o;
  }
}

extern "C" void kernel_launch(void* const* d_in, const int* in_sizes, int n_in,
                              void* d_out, int out_size, void* d_ws, size_t ws_size,
                              hipStream_t stream) {
  const float* fv  = (const float*)d_in[0];  // (B,C,H,W)
  const float* pi  = (const float*)d_in[1];  // (B,4,H,W)
  const int*   pm  = (const int*)d_in[2];    // (B,H,W)
  const float* pif = (const float*)d_in[3];  // (B,4,H,W)
  const int*   pmf = (const int*)d_in[4];    // (B,H,W)
  float* out = (float*)d_out;                // (B,C,NY,NX) f32

  // workspace layout (16B aligned): small buffers < 8 MB, acc 134 MB at +8MB.
  char* wsb = (char*)d_ws;
  float*  fvT    = (float*)(wsb);                 // B*HW*C*4      = 4,194,304
  float*  cnt    = (float*)(wsb + 4194304);       // B*NYNX*4      = 2,097,152
  float4* near4  = (float4*)(wsb + 6291456);      // B*N*16        =   262,144
  float4* far4   = (float4*)(wsb + 6553600);      // B*N*16        =   262,144
  float4* nearnn = (float4*)(wsb + 6815744);      // B*N*16        =   262,144
  int*    cstart = (int*)(wsb + 7471104);         // B*(1024+1)*4  =     8,320
  int*    gidx   = (int*)(wsb + 7479424);         // B*N*4         =    65,536
  float4* gpts   = (float4*)(wsb + 7544960);      // B*N*16        =   262,144
  float*  acc    = (float*)(wsb + 8388608);       // B*NYNX*C*4    = 134,217,728

  hipMemsetAsync(cnt, 0, (size_t)B_ * NYNX_ * sizeof(float), stream);

  prep_kernel<<<320, 256, 0, stream>>>(
      fv, pi, pm, pif, pmf, near4, far4, nearnn, cnt, fvT);
  build_grid_kernel<<<B_ + B_ * NYNX_ / 256, 256, 0, stream>>>(
      nearnn, cnt, cstart, gpts, gidx, acc);
  nn_scatter_kernel<<<NNB_ + B_ * N_ / 4, 256, 0, stream>>>(
      far4, cstart, gpts, gidx, near4, fvT, cnt, acc);
  emit_kernel<<<dim3(NYNX_ / 64, B_), 256, 0, stream>>>(acc, cnt, out);
}

// Round 14
// 202.010 us; speedup vs baseline: 1.1785x; 1.0116x over previous
//
#include <hip/hip_runtime.h>
#include <math.h>

// Problem constants (match the jax reference)
constexpr int B_  = 2;
constexpr int C_  = 64;
constexpr int HW_ = 64 * 128;      // 8192
constexpr int N_  = HW_;           // points per image (near == far == 8192)
constexpr int NX_ = 512;
constexpr int NY_ = 512;
constexpr int NYNX_ = NX_ * NY_;   // 262144
constexpr int GC_  = 32;           // NN search grid is GC x GC cells of 1.6 m
constexpr int GCC_ = GC_ * GC_;    // 1024 cells
constexpr int LPF_ = 8;            // lanes per far point in nn_search
constexpr int BN_  = B_ * N_;      // 16384
constexpr int NNB_ = BN_ / (256 / LPF_);   // 512 NN blocks (32 far pts/block)

// ---------------------------------------------------------------------------
// Shared voxel binning (numpy f32 bitwise). -1 = contributes nothing.
// ---------------------------------------------------------------------------
__device__ __forceinline__ int voxel_of(float x, float y, float w) {
#pragma clang fp contract(off)
  if (w == 0.0f) return -1;
  float qx = (x - 0.0f) / 0.1f;
  float qy = (y - (-25.6f)) / 0.1f;
  int ix = (int)floorf(qx);
  int iy = (int)floorf(qy);
  if (ix < 0 || ix >= NX_ || iy < 0 || iy >= NY_) return -1;
  return iy * NX_ + ix;
}

// NN-grid cell coords (internal only — must be identical in build & search).
__device__ __forceinline__ int gcell_x(float x) {
  int c = (int)floorf(x * 0.625f);          // /1.6
  return min(GC_ - 1, max(0, c));
}
__device__ __forceinline__ int gcell_y(float y) {
  int c = (int)floorf((y + 25.6f) * 0.625f);
  return min(GC_ - 1, max(0, c));
}

// ---------------------------------------------------------------------------
// Fused prep: blocks [0,64) pack+count points AND build the per-batch NN-cell
// histogram (full-width — removes build_grid's serial count pass);
// blocks [64,320) transpose fv (B,C,HW) -> fvT (B,HW,C). Halves independent.
// ---------------------------------------------------------------------------
__global__ __launch_bounds__(256) void prep_kernel(
    const float* __restrict__ fv,
    const float* __restrict__ pi, const int* __restrict__ pm,
    const float* __restrict__ pif, const int* __restrict__ pmf,
    float4* __restrict__ near4, float4* __restrict__ far4,
    float4* __restrict__ nearnn, float* __restrict__ cnt,
    int* __restrict__ gcellcnt, int* __restrict__ pcell,
    float* __restrict__ fvT) {
#pragma clang fp contract(off)
  __shared__ float tile[64][65];
  if (blockIdx.x < 64) {
    // ---- pack + count + cell histogram ----
    int t = blockIdx.x * 256 + threadIdx.x;        // over B_*N_
    int k = t / N_, n = t % N_;
    const float* base  = pi  + (size_t)k * 4 * HW_;
    const float* basef = pif + (size_t)k * 4 * HW_;
    float x = base[n], y = base[HW_ + n], z = base[2 * HW_ + n];
    bool v = pm[k * HW_ + n] > 0;
    near4[t] = make_float4(x, y, z, v ? 1.0f : 0.0f);
    float sq = (x * x + y * y) + z * z;   // numpy 3-elem sum order
    nearnn[t] = v ? make_float4(x, y, z, sq)
                 : make_float4(0.0f, 0.0f, 0.0f, 1e10f);
    float fx = basef[n], fy = basef[HW_ + n], fz = basef[2 * HW_ + n];
    bool vf = pmf[k * HW_ + n] > 0;
    far4[t] = make_float4(fx, fy, fz, vf ? 1.0f : 0.0f);

    // NN-cell id for valid near points (-1 masked) + histogram
    if (v) {
      int c = gcell_y(y) * GC_ + gcell_x(x);
      pcell[t] = c;
      atomicAdd(&gcellcnt[k * GCC_ + c], 1);
    } else {
      pcell[t] = -1;
    }

    int vn = voxel_of(x, y, v ? 1.0f : 0.0f);
    if (vn >= 0) atomicAdd(&cnt[(size_t)k * NYNX_ + vn], 1.0f);
    int vfv = voxel_of(fx, fy, vf ? 1.0f : 0.0f);
    if (vfv >= 0) atomicAdd(&cnt[(size_t)k * NYNX_ + vfv], 1.0f);
  } else {
    // ---- transpose ----
    int bid = blockIdx.x - 64;          // 0..255
    int k = bid >> 7;                   // /128
    int n0 = (bid & 127) * 64;
    int tx = threadIdx.x & 63, ty = threadIdx.x >> 6;
    for (int c = ty; c < C_; c += 4)
      tile[c][tx] = fv[((size_t)(k * C_ + c)) * HW_ + n0 + tx];
    __syncthreads();
    for (int nn = ty; nn < 64; nn += 4)
      fvT[((size_t)(k * HW_ + n0 + nn)) * C_ + tx] = tile[tx][nn];
  }
}

// ---------------------------------------------------------------------------
// Lexicographic stable top-3 insert on (value, index): lower value wins,
// ties broken by lower index. Order-INDEPENDENT (safe for arbitrary candidate
// order) and equal to jax stable top-k. Invariant: slots lex-sorted.
// ---------------------------------------------------------------------------
__device__ __forceinline__ void merge3L(float tv, int idx,
                                        float& b0, float& b1, float& b2,
                                        int& i0, int& i1, int& i2) {
  bool w0 = (tv < b0) || (tv == b0 && idx < i0);
  bool w1 = (tv < b1) || (tv == b1 && idx < i1);
  bool w2 = (tv < b2) || (tv == b2 && idx < i2);
  float ob0 = b0, ob1 = b1;
  int   oi0 = i0, oi1 = i1;
  b0 = w0 ? tv : b0;                    i0 = w0 ? idx : i0;
  b1 = w0 ? ob0 : (w1 ? tv : b1);       i1 = w0 ? oi0 : (w1 ? idx : i1);
  b2 = w1 ? ob1 : (w2 ? tv : b2);       i2 = w1 ? oi1 : (w2 ? idx : i2);
}

// ---------------------------------------------------------------------------
// build_grid: blocks [0,B_) scan the precomputed cell histogram and fill the
// CSR (single pass over pcell/nearnn — count pass eliminated, done in prep).
// Within-cell order arbitrary (atomic cursors) — selection is lexicographic.
// Blocks [B_, B_+2048): zero acc rows where cnt>=2 (~130 voxels/batch).
// ---------------------------------------------------------------------------
__global__ __launch_bounds__(256) void build_grid_kernel(
    const float4* __restrict__ nearnn, const int* __restrict__ gcellcnt,
    const int* __restrict__ pcell, const float* __restrict__ cnt,
    int* __restrict__ cell_start, float4* __restrict__ gpts,
    int* __restrict__ gidx, float* __restrict__ acc) {
  __shared__ int lcnt[GCC_];
  __shared__ int lsum[256];
  __shared__ int lcur[GCC_];
  int t = threadIdx.x;
  if (blockIdx.x < (unsigned)B_) {
    int k = blockIdx.x;
    // scan: per-thread 4-elem serial + Hillis-Steele over 256 partials
    int base = t * 4;
    const int* gc = gcellcnt + k * GCC_;
    int c0 = gc[base], c1 = gc[base + 1], c2 = gc[base + 2], c3 = gc[base + 3];
    int s = c0 + c1 + c2 + c3;
    lsum[t] = s;
    __syncthreads();
    for (int off = 1; off < 256; off <<= 1) {
      int v = (t >= off) ? lsum[t - off] : 0;
      __syncthreads();
      lsum[t] += v;
      __syncthreads();
    }
    int ex = lsum[t] - s;                 // exclusive prefix of this thread's 4
    lcnt[base] = ex;
    lcnt[base + 1] = ex + c0;
    lcnt[base + 2] = ex + c0 + c1;
    lcnt[base + 3] = ex + c0 + c1 + c2;
    __syncthreads();
    for (int i = t; i < GCC_; i += 256) {
      cell_start[k * (GCC_ + 1) + i] = lcnt[i];
      lcur[i] = lcnt[i];
    }
    if (t == 255) cell_start[k * (GCC_ + 1) + GCC_] = lsum[255];
    __syncthreads();
    // fill (single pass; cell ids precomputed in prep)
    for (int n = t; n < N_; n += 256) {
      int c = pcell[k * N_ + n];
      if (c >= 0) {
        int p = atomicAdd(&lcur[c], 1);
        gpts[k * N_ + p] = nearnn[k * N_ + n];
        gidx[k * N_ + p] = n;
      }
    }
  } else {
    int tt = (blockIdx.x - B_) * 256 + t;   // over B_*NYNX_
    if (cnt[tt] >= 2.0f) {
      float4* row = (float4*)(acc + (size_t)tt * C_);
      float4 z = make_float4(0.0f, 0.0f, 0.0f, 0.0f);
      for (int i = 0; i < C_ / 4; ++i) row[i] = z;
    }
  }
}

// ---------------------------------------------------------------------------
// Fused NN + scatter.
// Blocks [0, NNB_): exact 3-NN (expanding Chebyshev rings, 8 lanes/far) then
// the SAME octet gathers the three fvT rows (float4, coalesced) and writes
// the interpolated acc row ((i,w) broadcast in-register via shfl, bit-exact).
// Value expr identical to R12 scatter: (w0*a + w1*b) + w2*c, contract off.
// Blocks [NNB_, NNB_+4096): near-point scatter, wave/point, lane = channel.
// cnt==1 rows (98%) are plain stores (single writer); cnt>=2 rows atomics.
// ---------------------------------------------------------------------------
__global__ __launch_bounds__(256) void nn_scatter_kernel(
    const float4* __restrict__ far4, const int* __restrict__ cell_start,
    const float4* __restrict__ gpts, const int* __restrict__ gidx,
    const float4* __restrict__ near4, const float* __restrict__ fvT,
    const float* __restrict__ cnt, float* __restrict__ acc) {
#pragma clang fp contract(off)
  int tid = threadIdx.x;
  if (blockIdx.x < (unsigned)NNB_) {
    int q = tid & (LPF_ - 1);
    int g = blockIdx.x * (256 / LPF_) + (tid / LPF_);   // far point id over BN
    int k = g >> 13;                        // /8192
    int m = g & (N_ - 1);

    float4 f = far4[k * N_ + m];
    float sf = (f.x * f.x + f.y * f.y) + f.z * f.z;   // numpy 3-elem order
    float ax = 2.0f * f.x, ay = 2.0f * f.y, az = 2.0f * f.z;
    int fcx = gcell_x(f.x), fcy = gcell_y(f.y);
    const int* cs_ = cell_start + k * (GCC_ + 1);

    float b0 = 1e30f, b1 = 1e30f, b2 = 1e30f;
    int i0 = 0, i1 = 0, i2 = 0;

    for (int r = 0; r < GC_; ++r) {
      int nc = (r == 0) ? 1 : 8 * r;
      for (int i = q; i < nc; i += LPF_) {
        int dx, dy;
        if (r == 0)            { dx = 0;             dy = 0; }
        else if (i < 2*r + 1)  { dx = i - r;         dy = -r; }
        else if (i < 4*r + 2)  { dx = i - (3*r + 1); dy = r; }
        else if (i < 6*r + 1)  { dx = -r;            dy = i - (5*r + 1); }
        else                   { dx = r;             dy = i - 7*r; }
        int cx = fcx + dx, cy = fcy + dy;
        if (cx < 0 || cx >= GC_ || cy < 0 || cy >= GC_) continue;
        int c = cy * GC_ + cx;
        int s = cs_[c], e = cs_[c + 1];
        for (int j = s; j < e; ++j) {
          float4 p = gpts[k * N_ + j];
          int idx = gidx[k * N_ + j];
          float p0 = ax * p.x;                                  // round(ax*px)
          float mm = __builtin_fmaf(az, p.z, __builtin_fmaf(ay, p.y, p0));
          float tv = (sf + p.w) - mm;
          merge3L(tv, idx, b0, b1, b2, i0, i1, i2);
        }
      }
      // octet-shared conservative bound (min of lanes' 3rd-best; 1e30 until
      // some lane holds 3 -> keep expanding, always safe)
      float s2 = b2;
      s2 = fminf(s2, __shfl_xor(s2, 1));
      s2 = fminf(s2, __shfl_xor(s2, 2));
      s2 = fminf(s2, __shfl_xor(s2, 4));
      float rd = (float)r * 1.6f;
      if (rd * rd > s2 + 0.01f) break;
    }

    // octet merge on lane 0 (lexicographic, order-independent)
    int base = tid & ~(LPF_ - 1);
    for (int s = 1; s < LPF_; ++s) {
      float v0 = __shfl(b0, base + s), v1 = __shfl(b1, base + s), v2 = __shfl(b2, base + s);
      int   j0 = __shfl(i0, base + s), j1 = __shfl(i1, base + s), j2 = __shfl(i2, base + s);
      if (q == 0) {
        merge3L(v0, j0, b0, b1, b2, i0, i1, i2);
        merge3L(v1, j1, b0, b1, b2, i0, i1, i2);
        merge3L(v2, j2, b0, b1, b2, i0, i1, i2);
      }
    }
    // weights on lane 0 (exactly as reference), then broadcast bit-exact
    float w0_ = 0.0f, w1_ = 0.0f, w2_ = 0.0f;
    if (q == 0) {
      float r0 = 1.0f / (b0 + 1e-8f);
      float r1 = 1.0f / (b1 + 1e-8f);
      float r2 = 1.0f / (b2 + 1e-8f);
      float rs = (r0 + r1) + r2;
      w0_ = r0 / rs; w1_ = r1 / rs; w2_ = r2 / rs;
    }
    float w0 = __shfl(w0_, base), w1 = __shfl(w1_, base), w2 = __shfl(w2_, base);
    int   j0 = __shfl(i0, base),  j1 = __shfl(i1, base),  j2 = __shfl(i2, base);

    // far-point scatter: octet handles the 64-channel row, lane q owns
    // float4 chunks {2q, 2q+1} (coalesced 256 B per row).
    int v = voxel_of(f.x, f.y, f.w);
    if (v < 0) return;
    float cn = cnt[(size_t)k * NYNX_ + v];
    const float4* r0p = (const float4*)(fvT + ((size_t)(k * N_ + j0)) * C_);
    const float4* r1p = (const float4*)(fvT + ((size_t)(k * N_ + j1)) * C_);
    const float4* r2p = (const float4*)(fvT + ((size_t)(k * N_ + j2)) * C_);
    size_t rowoff = ((size_t)k * NYNX_ + v) * C_;
#pragma unroll
    for (int h = 0; h < 2; ++h) {
      int c4 = q * 2 + h;
      float4 a = r0p[c4], b = r1p[c4], c = r2p[c4];
      float4 val;
      val.x = (w0 * a.x + w1 * b.x) + w2 * c.x;
      val.y = (w0 * a.y + w1 * b.y) + w2 * c.y;
      val.z = (w0 * a.z + w1 * b.z) + w2 * c.z;
      val.w = (w0 * a.w + w1 * b.w) + w2 * c.w;
      if (cn == 1.0f) {
        ((float4*)(acc + rowoff))[c4] = val;
      } else {
        float* p = acc + rowoff + c4 * 4;
        atomicAdd(p + 0, val.x); atomicAdd(p + 1, val.y);
        atomicAdd(p + 2, val.z); atomicAdd(p + 3, val.w);
      }
    }
  } else {
    // ---- near-point scatter: wave per point, lane = channel ----
    int lane = tid & 63;
    int wv = (blockIdx.x - NNB_) * 4 + (tid >> 6);  // 0..BN_-1
    int k = wv >> 13;
    int n = wv & (N_ - 1);
    float4 pt = near4[k * N_ + n];
    int v = voxel_of(pt.x, pt.y, pt.w);
    if (v < 0) return;
    float val = fvT[((size_t)(k * N_ + n)) * C_ + lane];
    size_t rowoff = ((size_t)k * NYNX_ + v) * C_;
    float cn = cnt[(size_t)k * NYNX_ + v];   // wave-uniform
    if (cn == 1.0f) acc[rowoff + lane] = val;
    else            atomicAdd(&acc[rowoff + lane], val);
  }
}

// ---------------------------------------------------------------------------
// Emit out (B,C,NY,NX) from acc/cnt via LDS transpose. Per block: 64 voxels.
// Covers every out element exactly once (fuses the zero-fill + mean divide).
// ---------------------------------------------------------------------------
__global__ __launch_bounds__(256) void emit_kernel(
    const float* __restrict__ acc, const float* __restrict__ cnt,
    float* __restrict__ out) {
#pragma clang fp contract(off)
  __shared__ float tile[64][65];
  __shared__ float cs[64];
  int t = threadIdx.x;
  int k = blockIdx.y;
  int v0 = blockIdx.x * 64;

  if (t < 64) cs[t] = cnt[(size_t)k * NYNX_ + v0 + t];
  __syncthreads();

  const float4* acc4 = (const float4*)acc;
#pragma unroll
  for (int p = 0; p < 4; ++p) {
    int row = p * 16 + (t >> 4);     // voxel within block
    int f4  = t & 15;                // float4 within the 64-channel row
    float c = cs[row];
    float4 a = make_float4(0.0f, 0.0f, 0.0f, 0.0f);
    if (c > 0.0f) {
      a = acc4[((size_t)k * NYNX_ + v0 + row) * (C_ / 4) + f4];
      a.x /= c; a.y /= c; a.z /= c; a.w /= c;
    }
    tile[f4 * 4 + 0][row] = a.x;
    tile[f4 * 4 + 1][row] = a.y;
    tile[f4 * 4 + 2][row] = a.z;
    tile[f4 * 4 + 3][row] = a.w;
  }
  __syncthreads();

#pragma unroll
  for (int p = 0; p < 4; ++p) {
    int c  = p * 16 + (t >> 4);      // channel
    int xq = t & 15;                 // float4 of voxels
    float4 o = make_float4(tile[c][xq * 4 + 0], tile[c][xq * 4 + 1],
                           tile[c][xq * 4 + 2], tile[c][xq * 4 + 3]);
    ((float4*)out)[(((size_t)k * C_ + c) * NYNX_ + v0) / 4 + xq] = o;
  }
}

extern "C" void kernel_launch(void* const* d_in, const int* in_sizes, int n_in,
                              void* d_out, int out_size, void* d_ws, size_t ws_size,
                              hipStream_t stream) {
  const float* fv  = (const float*)d_in[0];  // (B,C,H,W)
  const float* pi  = (const float*)d_in[1];  // (B,4,H,W)
  const int*   pm  = (const int*)d_in[2];    // (B,H,W)
  const float* pif = (const float*)d_in[3];  // (B,4,H,W)
  const int*   pmf = (const int*)d_in[4];    // (B,H,W)
  float* out = (float*)d_out;                // (B,C,NY,NX) f32

  // workspace layout (16B aligned): small buffers < 8 MB, acc 134 MB at +8MB.
  // cnt and gcellcnt are ADJACENT so one memset zeroes both.
  char* wsb = (char*)d_ws;
  float*  fvT    = (float*)(wsb);                 // 4,194,304
  float*  cnt    = (float*)(wsb + 4194304);       // 2,097,152
  int*    gcell  = (int*)(wsb + 6291456);         // B*1024*4 = 8,192
  int*    pcell  = (int*)(wsb + 6299648);         // B*N*4    = 65,536
  float4* near4  = (float4*)(wsb + 6365184);      // 262,144
  float4* far4   = (float4*)(wsb + 6627328);      // 262,144
  float4* nearnn = (float4*)(wsb + 6889472);      // 262,144
  int*    cstart = (int*)(wsb + 7151616);         // 8,320
  int*    gidx   = (int*)(wsb + 7159936);         // 65,536
  float4* gpts   = (float4*)(wsb + 7225472);      // 262,144
  float*  acc    = (float*)(wsb + 8388608);       // 134,217,728

  // one memset covers cnt (2,097,152 B) + gcellcnt (8,192 B)
  hipMemsetAsync(cnt, 0, 2097152 + 8192, stream);

  prep_kernel<<<320, 256, 0, stream>>>(
      fv, pi, pm, pif, pmf, near4, far4, nearnn, cnt, gcell, pcell, fvT);
  build_grid_kernel<<<B_ + B_ * NYNX_ / 256, 256, 0, stream>>>(
      nearnn, gcell, pcell, cnt, cstart, gpts, gidx, acc);
  nn_scatter_kernel<<<NNB_ + B_ * N_ / 4, 256, 0, stream>>>(
      far4, cstart, gpts, gidx, near4, fvT, cnt, acc);
  emit_kernel<<<dim3(NYNX_ / 64, B_), 256, 0, stream>>>(acc, cnt, out);
}